// Round 1
// baseline (886.899 us; speedup 1.0000x reference)
//
#include <hip/hip_runtime.h>
#include <cstdint>

#define B_SZ 4
#define S_LEN 1024
#define DIM 4096
#define NH 32
#define KVH 8
#define HD 128
#define DQKV 6144  // 4096 Q + 1024 K + 1024 V

typedef __bf16 bf16x8 __attribute__((ext_vector_type(8)));
typedef float f32x4 __attribute__((ext_vector_type(4)));

__device__ __forceinline__ unsigned short f2bf(float f) {
  union { float f; uint32_t u; } v; v.f = f;
  uint32_t u = v.u;
  return (unsigned short)((u + 0x7fffu + ((u >> 16) & 1u)) >> 16);
}
__device__ __forceinline__ float bf2f(unsigned short h) {
  union { uint32_t u; float f; } v; v.u = ((uint32_t)h) << 16;
  return v.f;
}

// async global->LDS, 16B per lane; lds must be wave-uniform base (dest = base + lane*16)
__device__ __forceinline__ void async16(void* lds, const void* g) {
  __builtin_amdgcn_global_load_lds(
      (const __attribute__((address_space(1))) void*)g,
      (__attribute__((address_space(3))) void*)lds, 16, 0, 0);
}

// ---------------- elementwise f32 -> bf16 ----------------
__global__ void cvt_x_kernel(const float* __restrict__ x, unsigned short* __restrict__ xb) {
  size_t i = ((size_t)blockIdx.x * 256 + threadIdx.x) * 4;
  float4 v = *(const float4*)(x + i);
  ushort4 o;
  o.x = f2bf(v.x); o.y = f2bf(v.y); o.z = f2bf(v.z); o.w = f2bf(v.w);
  *(ushort4*)(xb + i) = o;
}

// ---------------- weight transpose+convert: w (K x N f32) -> wt (N x K bf16, ld=4096) ----
__global__ void wtrans_kernel(const float* __restrict__ w, unsigned short* __restrict__ wt, int N) {
  __shared__ __align__(16) float tile[32][33];
  int n0 = blockIdx.x * 32, k0 = blockIdx.y * 32;
  int tx = threadIdx.x & 31, ty = threadIdx.x >> 5;
#pragma unroll
  for (int i = 0; i < 4; i++) {
    int k = ty + i * 8;
    tile[k][tx] = w[(size_t)(k0 + k) * N + n0 + tx];
  }
  __syncthreads();
#pragma unroll
  for (int i = 0; i < 4; i++) {
    int n = ty + i * 8;
    wt[(size_t)(n0 + n) * DIM + k0 + tx] = f2bf(tile[tx][n]);
  }
}

// ---------------- m97-style GEMM: C(MxN) = A(MxK bf16) * Bt(NxK bf16)^T ----------------
// 128x128 tile, BK=32, 256 thr = 4 waves (2x2), 4x4 16x16x32 MFMA frags per wave.
template <bool OUT_BF16>
__global__ __launch_bounds__(256, 2) void gemm_bt_kernel(
    const unsigned short* __restrict__ A, const unsigned short* __restrict__ Bt,
    void* __restrict__ Cout, int Kdim, int ldc) {
  __shared__ __align__(16) unsigned short lA[128 * 32];
  __shared__ __align__(16) unsigned short lB[128 * 32];
  const int tid = threadIdx.x;
  const int wave = tid >> 6, lane = tid & 63;
  const int m0 = blockIdx.y * 128, n0 = blockIdx.x * 128;
  // staging: chunk c = tid (+256); row = c>>2, col = (c&3)*8
  const int r0 = tid >> 2, c0 = (tid & 3) * 8;
  const unsigned short* gA0 = A + (size_t)(m0 + r0) * Kdim + c0;
  const unsigned short* gA1 = gA0 + (size_t)64 * Kdim;
  const unsigned short* gB0 = Bt + (size_t)(n0 + r0) * Kdim + c0;
  const unsigned short* gB1 = gB0 + (size_t)64 * Kdim;
  unsigned short* lA0 = lA + wave * 512;
  unsigned short* lA1 = lA + 2048 + wave * 512;
  unsigned short* lB0 = lB + wave * 512;
  unsigned short* lB1 = lB + 2048 + wave * 512;
  const int wm = (wave & 1) * 64, wn = (wave >> 1) * 64;
  const int lql = lane & 15, lqh = lane >> 4;
  f32x4 acc[4][4] = {};
  for (int kk = 0; kk < Kdim; kk += 32) {
    __syncthreads();
    async16(lA0, gA0 + kk);
    async16(lA1, gA1 + kk);
    async16(lB0, gB0 + kk);
    async16(lB1, gB1 + kk);
    __syncthreads();
    bf16x8 af[4], bfr[4];
#pragma unroll
    for (int mi = 0; mi < 4; mi++)
      af[mi] = *(const bf16x8*)(lA + (wm + mi * 16 + lql) * 32 + lqh * 8);
#pragma unroll
    for (int ni = 0; ni < 4; ni++)
      bfr[ni] = *(const bf16x8*)(lB + (wn + ni * 16 + lql) * 32 + lqh * 8);
#pragma unroll
    for (int mi = 0; mi < 4; mi++)
#pragma unroll
      for (int ni = 0; ni < 4; ni++)
        acc[mi][ni] = __builtin_amdgcn_mfma_f32_16x16x32_bf16(af[mi], bfr[ni], acc[mi][ni], 0, 0, 0);
  }
  // C/D layout: row = (lane>>4)*4 + reg, col = lane&15  [verified m89/m91]
#pragma unroll
  for (int mi = 0; mi < 4; mi++)
#pragma unroll
    for (int ni = 0; ni < 4; ni++)
#pragma unroll
      for (int r = 0; r < 4; r++) {
        int row = m0 + wm + mi * 16 + lqh * 4 + r;
        int col = n0 + wn + ni * 16 + lql;
        float v = acc[mi][ni][r];
        if (OUT_BF16)
          ((unsigned short*)Cout)[(size_t)row * ldc + col] = f2bf(v);
        else
          ((float*)Cout)[(size_t)row * ldc + col] = v;
      }
}

// ---------------- RoPE + relayout: qkv rows (token, DQKV) -> (B, H, S, HD), optional scale
__global__ void rope_kernel(const unsigned short* __restrict__ src, const float* __restrict__ fc,
                            const float* __restrict__ fs, unsigned short* __restrict__ dst,
                            int nheads, float scale) {
  int idx = blockIdx.x * 256 + threadIdx.x;
  int f = idx & 63;
  int rest = idx >> 6;
  int hh = rest % nheads;
  int t = rest / nheads;
  int s = t & (S_LEN - 1);
  int b = t >> 10;
  const unsigned short* p = src + (size_t)t * DQKV + hh * HD + 2 * f;
  ushort2 xv = *(const ushort2*)p;
  float xr = bf2f(xv.x), xi = bf2f(xv.y);
  float c = fc[s * 64 + f], sn = fs[s * 64 + f];
  ushort2 o;
  o.x = f2bf((xr * c - xi * sn) * scale);
  o.y = f2bf((xr * sn + xi * c) * scale);
  *(ushort2*)(dst + ((size_t)(b * nheads + hh) * S_LEN + s) * HD + 2 * f) = o;
}

// ---------------- V transpose: qkv V cols (token, kvh*HD+d) -> Vt (B,KVH,HD,S) ----------
__global__ void vtrans_kernel(const unsigned short* __restrict__ src, unsigned short* __restrict__ Vt) {
  __shared__ __align__(16) unsigned short tile[32][33];
  int s0 = blockIdx.x * 32, d0 = blockIdx.y * 32, bk = blockIdx.z;
  int tx = threadIdx.x & 31, ty = threadIdx.x >> 5;
#pragma unroll
  for (int i = 0; i < 4; i++) {
    int s = ty + i * 8;
    tile[s][tx] = src[(size_t)((bk >> 3) * S_LEN + s0 + s) * DQKV + (bk & 7) * HD + d0 + tx];
  }
  __syncthreads();
#pragma unroll
  for (int i = 0; i < 4; i++) {
    int d = ty + i * 8;
    Vt[((size_t)bk * HD + d0 + d) * S_LEN + s0 + tx] = tile[tx][d];
  }
}

// ---------------- flash attention (non-causal, full 1024 keys) ----------------
// block = 4 waves x 16 q-rows = 64 q-rows; K-tiles of 64 keys; online softmax intra-wave.
__global__ __launch_bounds__(256, 2) void attn_kernel(
    const unsigned short* __restrict__ Qb,  // (B,NH,S,HD), pre-scaled by 1/sqrt(HD)
    const unsigned short* __restrict__ Kb,  // (B,KVH,S,HD)
    const unsigned short* __restrict__ Vt,  // (B,KVH,HD,S)
    unsigned short* __restrict__ Ob) {      // (token, NH*HD)
  __shared__ __align__(16) unsigned short Kt[64][136];   // [key][d], padded (2-way max)
  __shared__ __align__(16) unsigned short Vl[128][72];   // [d][key], padded
  __shared__ __align__(16) unsigned short Pl[4][16][72]; // per-wave [q][key], padded
  const int tid = threadIdx.x, wave = tid >> 6, lane = tid & 63;
  const int qb = blockIdx.x, h = blockIdx.y, b = blockIdx.z;
  const int kvh = h >> 2;  // N_REP = 4
  const int lql = lane & 15, lqh = lane >> 4;
  const int qrow = qb * 64 + wave * 16;

  const unsigned short* Qp = Qb + ((size_t)(b * NH + h) * S_LEN + qrow + lql) * HD + lqh * 8;
  bf16x8 qf[4];
#pragma unroll
  for (int kd = 0; kd < 4; kd++) qf[kd] = *(const bf16x8*)(Qp + kd * 32);

  const unsigned short* Kp = Kb + (size_t)(b * KVH + kvh) * S_LEN * HD;
  const unsigned short* Vp = Vt + (size_t)(b * KVH + kvh) * HD * S_LEN;

  float m_run[4], l_run[4];
  f32x4 Oacc[8] = {};
#pragma unroll
  for (int r = 0; r < 4; r++) { m_run[r] = -3.0e38f; l_run[r] = 0.0f; }

  for (int kt = 0; kt < S_LEN; kt += 64) {
    __syncthreads();
    // stage K tile: 64 keys x 128 d
#pragma unroll
    for (int i = 0; i < 4; i++) {
      int c = tid + 256 * i;
      int key = c >> 4, doff = (c & 15) * 8;
      *(uint4*)(&Kt[key][doff]) = *(const uint4*)(Kp + (size_t)(kt + key) * HD + doff);
    }
    // stage V^T tile: 128 d x 64 keys
#pragma unroll
    for (int i = 0; i < 4; i++) {
      int c = tid + 256 * i;
      int d = c >> 3, koff = (c & 7) * 8;
      *(uint4*)(&Vl[d][koff]) = *(const uint4*)(Vp + (size_t)d * S_LEN + kt + koff);
    }
    __syncthreads();
    // S = Q K^T  (16 q x 64 keys per wave)
    f32x4 sf[4] = {};
#pragma unroll
    for (int ni = 0; ni < 4; ni++)
#pragma unroll
      for (int kd = 0; kd < 4; kd++) {
        bf16x8 kf = *(const bf16x8*)(&Kt[ni * 16 + lql][kd * 32 + lqh * 8]);
        sf[ni] = __builtin_amdgcn_mfma_f32_16x16x32_bf16(qf[kd], kf, sf[ni], 0, 0, 0);
      }
    // online softmax: row = lqh*4 + r, cols spread over 16 lanes (masks 1/2/4/8 stay in group)
    float mnew[4], alpha[4], psum[4];
#pragma unroll
    for (int r = 0; r < 4; r++) {
      float v = fmaxf(fmaxf(sf[0][r], sf[1][r]), fmaxf(sf[2][r], sf[3][r]));
      v = fmaxf(v, __shfl_xor(v, 1));
      v = fmaxf(v, __shfl_xor(v, 2));
      v = fmaxf(v, __shfl_xor(v, 4));
      v = fmaxf(v, __shfl_xor(v, 8));
      mnew[r] = fmaxf(m_run[r], v);
      alpha[r] = __expf(m_run[r] - mnew[r]);
      m_run[r] = mnew[r];
      psum[r] = 0.0f;
    }
#pragma unroll
    for (int ni = 0; ni < 4; ni++)
#pragma unroll
      for (int r = 0; r < 4; r++) {
        float p = __expf(sf[ni][r] - mnew[r]);
        psum[r] += p;
        Pl[wave][lqh * 4 + r][ni * 16 + lql] = f2bf(p);
      }
#pragma unroll
    for (int r = 0; r < 4; r++) {
      float v = psum[r];
      v += __shfl_xor(v, 1);
      v += __shfl_xor(v, 2);
      v += __shfl_xor(v, 4);
      v += __shfl_xor(v, 8);
      l_run[r] = l_run[r] * alpha[r] + v;
    }
#pragma unroll
    for (int ni = 0; ni < 8; ni++)
#pragma unroll
      for (int r = 0; r < 4; r++) Oacc[ni][r] *= alpha[r];
    // O += P V  (P from per-wave LDS in A-layout; same-wave DS ordering guarantees visibility)
    bf16x8 pa[2];
#pragma unroll
    for (int ks = 0; ks < 2; ks++)
      pa[ks] = *(const bf16x8*)(&Pl[wave][lql][ks * 32 + lqh * 8]);
#pragma unroll
    for (int ni = 0; ni < 8; ni++)
#pragma unroll
      for (int ks = 0; ks < 2; ks++) {
        bf16x8 vb = *(const bf16x8*)(&Vl[ni * 16 + lql][ks * 32 + lqh * 8]);
        Oacc[ni] = __builtin_amdgcn_mfma_f32_16x16x32_bf16(pa[ks], vb, Oacc[ni], 0, 0, 0);
      }
  }
#pragma unroll
  for (int r = 0; r < 4; r++) l_run[r] = 1.0f / l_run[r];
#pragma unroll
  for (int ni = 0; ni < 8; ni++)
#pragma unroll
    for (int r = 0; r < 4; r++) {
      int q = qrow + lqh * 4 + r;
      Ob[(size_t)(b * S_LEN + q) * DIM + h * HD + ni * 16 + lql] = f2bf(Oacc[ni][r] * l_run[r]);
    }
}

extern "C" void kernel_launch(void* const* d_in, const int* in_sizes, int n_in,
                              void* d_out, int out_size, void* d_ws, size_t ws_size,
                              hipStream_t stream) {
  (void)in_sizes; (void)n_in; (void)out_size; (void)ws_size;
  const float* x  = (const float*)d_in[0];
  const float* fc = (const float*)d_in[1];
  const float* fs = (const float*)d_in[2];
  const float* wq = (const float*)d_in[3];
  const float* wk = (const float*)d_in[4];
  const float* wv = (const float*)d_in[5];
  const float* wo = (const float*)d_in[6];
  // d_in[7] = start, always 0 in this problem
  float* out = (float*)d_out;
  char* ws = (char*)d_ws;

  const size_t MB = 1024 * 1024;
  // lifetimes allow aliasing: total ws use = 160 MB
  unsigned short* xb    = (unsigned short*)(ws + 0);         // 32MB; dead after gemm1
  unsigned short* attnb = (unsigned short*)(ws + 0);         // reuses xb slot
  unsigned short* wqkvt = (unsigned short*)(ws + 32 * MB);   // 48MB; dead after gemm1
  unsigned short* Qb    = (unsigned short*)(ws + 32 * MB);   // 32MB, reuses wqkvt
  unsigned short* Kb    = (unsigned short*)(ws + 64 * MB);   // 8MB
  unsigned short* Vt    = (unsigned short*)(ws + 72 * MB);   // 8MB
  unsigned short* wot   = (unsigned short*)(ws + 80 * MB);   // 32MB
  unsigned short* qkv   = (unsigned short*)(ws + 112 * MB);  // 48MB

  cvt_x_kernel<<<16384, 256, 0, stream>>>(x, xb);
  wtrans_kernel<<<dim3(128, 128), 256, 0, stream>>>(wq, wqkvt, 4096);
  wtrans_kernel<<<dim3(32, 128), 256, 0, stream>>>(wk, wqkvt + (size_t)4096 * 4096, 1024);
  wtrans_kernel<<<dim3(32, 128), 256, 0, stream>>>(wv, wqkvt + (size_t)5120 * 4096, 1024);
  wtrans_kernel<<<dim3(128, 128), 256, 0, stream>>>(wo, wot, 4096);
  // QKV projection: (4096 x 4096) @ (4096 x 6144) -> bf16
  gemm_bt_kernel<true><<<dim3(DQKV / 128, 32), 256, 0, stream>>>(xb, wqkvt, qkv, DIM, DQKV);
  // RoPE + relayout (scale folded into Q)
  rope_kernel<<<32768, 256, 0, stream>>>(qkv, fc, fs, Qb, NH, 0.08838834764831845f);
  rope_kernel<<<8192, 256, 0, stream>>>(qkv + 4096, fc, fs, Kb, KVH, 1.0f);
  vtrans_kernel<<<dim3(32, 4, 32), 256, 0, stream>>>(qkv + 5120, Vt);
  // attention
  attn_kernel<<<dim3(16, NH, B_SZ), 256, 0, stream>>>(Qb, Kb, Vt, attnb);
  // out projection: fp32 out
  gemm_bt_kernel<false><<<dim3(32, 32), 256, 0, stream>>>(attnb, wot, out, DIM, DIM);
}

// Round 3
// 804.240 us; speedup vs baseline: 1.1028x; 1.1028x over previous
//
#include <hip/hip_runtime.h>
#include <cstdint>

#define B_SZ 4
#define S_LEN 1024
#define DIM 4096
#define NH 32
#define KVH 8
#define HD 128
#define DQKV 6144  // 4096 Q + 1024 K + 1024 V

typedef __bf16 bf16x8 __attribute__((ext_vector_type(8)));
typedef float f32x4 __attribute__((ext_vector_type(4)));

__device__ __forceinline__ unsigned short f2bf(float f) {
  union { float f; uint32_t u; } v; v.f = f;
  uint32_t u = v.u;
  return (unsigned short)((u + 0x7fffu + ((u >> 16) & 1u)) >> 16);
}
__device__ __forceinline__ float bf2f(unsigned short h) {
  union { uint32_t u; float f; } v; v.u = ((uint32_t)h) << 16;
  return v.f;
}
__device__ __forceinline__ float ex2(float x) {
#if __has_builtin(__builtin_amdgcn_exp2f)
  return __builtin_amdgcn_exp2f(x);
#else
  return exp2f(x);
#endif
}

// async global->LDS, 16B per lane; LDS dest = wave-uniform base + lane*16
__device__ __forceinline__ void async16(void* lds, const void* g) {
  __builtin_amdgcn_global_load_lds(
      (const __attribute__((address_space(1))) void*)g,
      (__attribute__((address_space(3))) void*)lds, 16, 0, 0);
}

// ---------------- elementwise f32 -> bf16 ----------------
__global__ void cvt_x_kernel(const float* __restrict__ x, unsigned short* __restrict__ xb) {
  size_t i = ((size_t)blockIdx.x * 256 + threadIdx.x) * 4;
  float4 v = *(const float4*)(x + i);
  ushort4 o;
  o.x = f2bf(v.x); o.y = f2bf(v.y); o.z = f2bf(v.z); o.w = f2bf(v.w);
  *(ushort4*)(xb + i) = o;
}

// ---------------- weight transpose+convert: w (K x N f32) -> wt (N x K bf16, ld=4096) ----
__global__ void wtrans_kernel(const float* __restrict__ w, unsigned short* __restrict__ wt, int N) {
  __shared__ float tile[64][65];
  int n0 = blockIdx.x * 64, k0 = blockIdx.y * 64;
  int tx = threadIdx.x & 63, ty = threadIdx.x >> 6;
#pragma unroll
  for (int i = 0; i < 16; i++) {
    int k = ty + i * 4;
    tile[k][tx] = w[(size_t)(k0 + k) * N + n0 + tx];
  }
  __syncthreads();
  int c = threadIdx.x & 31, ny = threadIdx.x >> 5;
#pragma unroll
  for (int i = 0; i < 8; i++) {
    int n = ny + i * 8;
    ushort2 o;
    o.x = f2bf(tile[2 * c][n]);
    o.y = f2bf(tile[2 * c + 1][n]);
    *(ushort2*)(wt + (size_t)(n0 + n) * DIM + k0 + 2 * c) = o;
  }
}

// ---------------- m97-style GEMM + XOR bank swizzle: C(MxN) = A(MxK) * Bt(NxK)^T -------
// LDS[r][p] holds k-chunk (p ^ ((r>>1)&3)) of row r; frag read at lqh ^ ((lql>>1)&3).
// This makes each 16-lane ds_read_b128 phase hit all 8 bank-quads (2-way = free, m136).
template <bool OUT_BF16>
__global__ __launch_bounds__(256, 2) void gemm_bt_kernel(
    const unsigned short* __restrict__ A, const unsigned short* __restrict__ Bt,
    void* __restrict__ Cout, int Kdim, int ldc) {
  __shared__ __align__(16) unsigned short lA[128 * 32];
  __shared__ __align__(16) unsigned short lB[128 * 32];
  const int tid = threadIdx.x;
  const int wave = tid >> 6, lane = tid & 63;
  const int m0 = blockIdx.y * 128, n0 = blockIdx.x * 128;
  // staging: lane covers row r0 = tid>>2, physical chunk p = tid&3; source chunk p^swz(r0)
  const int r0 = tid >> 2;
  const int c0 = ((tid & 3) ^ ((tid >> 3) & 3)) * 8;  // (p ^ ((r0>>1)&3)) * 8
  const unsigned short* gA0 = A + (size_t)(m0 + r0) * Kdim + c0;
  const unsigned short* gA1 = gA0 + (size_t)64 * Kdim;
  const unsigned short* gB0 = Bt + (size_t)(n0 + r0) * Kdim + c0;
  const unsigned short* gB1 = gB0 + (size_t)64 * Kdim;
  unsigned short* lA0 = lA + wave * 512;
  unsigned short* lA1 = lA + 2048 + wave * 512;
  unsigned short* lB0 = lB + wave * 512;
  unsigned short* lB1 = lB + 2048 + wave * 512;
  const int wm = (wave & 1) * 64, wn = (wave >> 1) * 64;
  const int lql = lane & 15, lqh = lane >> 4;
  const int ksw = (lqh ^ ((lql >> 1) & 3)) * 8;  // physical chunk offset for k-chunk lqh
  f32x4 acc[4][4] = {};
  for (int kk = 0; kk < Kdim; kk += 32) {
    __syncthreads();
    async16(lA0, gA0 + kk);
    async16(lA1, gA1 + kk);
    async16(lB0, gB0 + kk);
    async16(lB1, gB1 + kk);
    __syncthreads();
    bf16x8 af[4], bfr[4];
#pragma unroll
    for (int mi = 0; mi < 4; mi++)
      af[mi] = *(const bf16x8*)(lA + (wm + mi * 16 + lql) * 32 + ksw);
#pragma unroll
    for (int ni = 0; ni < 4; ni++)
      bfr[ni] = *(const bf16x8*)(lB + (wn + ni * 16 + lql) * 32 + ksw);
#pragma unroll
    for (int mi = 0; mi < 4; mi++)
#pragma unroll
      for (int ni = 0; ni < 4; ni++)
        acc[mi][ni] = __builtin_amdgcn_mfma_f32_16x16x32_bf16(af[mi], bfr[ni], acc[mi][ni], 0, 0, 0);
  }
  // C/D layout: row = (lane>>4)*4 + reg, col = lane&15  [verified m89/m91]
#pragma unroll
  for (int mi = 0; mi < 4; mi++)
#pragma unroll
    for (int ni = 0; ni < 4; ni++)
#pragma unroll
      for (int r = 0; r < 4; r++) {
        int row = m0 + wm + mi * 16 + lqh * 4 + r;
        int col = n0 + wn + ni * 16 + lql;
        float v = acc[mi][ni][r];
        if (OUT_BF16)
          ((unsigned short*)Cout)[(size_t)row * ldc + col] = f2bf(v);
        else
          ((float*)Cout)[(size_t)row * ldc + col] = v;
      }
}

// ---------------- RoPE + relayout: qkv rows (token, DQKV) -> (B, H, S, HD) -------------
// 4 (r,i) pairs per thread, 16B loads/stores. Scale folded into Q (incl. log2e).
__global__ void rope_kernel(const unsigned short* __restrict__ src, const float* __restrict__ fc,
                            const float* __restrict__ fs, unsigned short* __restrict__ dst,
                            int nheads, int hshift, float scale) {
  int idx = blockIdx.x * 256 + threadIdx.x;
  int f4 = idx & 15;
  int rest = idx >> 4;
  int hh = rest & (nheads - 1);
  int t = rest >> hshift;
  int s = t & (S_LEN - 1);
  int b = t >> 10;
  union { uint4 v; unsigned short u[8]; } in, out;
  in.v = *(const uint4*)(src + (size_t)t * DQKV + hh * HD + f4 * 8);
  union { float4 v; float f[4]; } c4, s4;
  c4.v = *(const float4*)(fc + s * 64 + f4 * 4);
  s4.v = *(const float4*)(fs + s * 64 + f4 * 4);
#pragma unroll
  for (int j = 0; j < 4; j++) {
    float xr = bf2f(in.u[2 * j]), xi = bf2f(in.u[2 * j + 1]);
    float cc = c4.f[j], ss = s4.f[j];
    out.u[2 * j] = f2bf((xr * cc - xi * ss) * scale);
    out.u[2 * j + 1] = f2bf((xr * ss + xi * cc) * scale);
  }
  *(uint4*)(dst + ((size_t)(b * nheads + hh) * S_LEN + s) * HD + f4 * 8) = out.v;
}

// ---------------- V transpose: qkv V cols (token, kvh*HD+d) -> Vt (B,KVH,HD,S) ----------
__global__ void vtrans_kernel(const unsigned short* __restrict__ src, unsigned short* __restrict__ Vt) {
  __shared__ __align__(16) unsigned short tile[32][33];
  int s0 = blockIdx.x * 32, d0 = blockIdx.y * 32, bk = blockIdx.z;
  int tx = threadIdx.x & 31, ty = threadIdx.x >> 5;
#pragma unroll
  for (int i = 0; i < 4; i++) {
    int s = ty + i * 8;
    tile[s][tx] = src[(size_t)((bk >> 3) * S_LEN + s0 + s) * DQKV + (bk & 7) * HD + d0 + tx];
  }
  __syncthreads();
#pragma unroll
  for (int i = 0; i < 4; i++) {
    int d = ty + i * 8;
    Vt[((size_t)bk * HD + d0 + d) * S_LEN + s0 + tx] = tile[tx][d];
  }
}

// ---------------- flash attention (non-causal, full 1024 keys) ----------------
// 4 waves x 16 q-rows; K-tiles of 64 keys; log2-domain online softmax (Q pre-scaled by
// log2e/sqrt(HD)). K/V staged via swizzled global_load_lds: row r's chunk c stored at
// physical c ^ (r&7) -> conflict-free frag reads.
__global__ __launch_bounds__(256, 3) void attn_kernel(
    const unsigned short* __restrict__ Qb,  // (B,NH,S,HD)
    const unsigned short* __restrict__ Kb,  // (B,KVH,S,HD)
    const unsigned short* __restrict__ Vt,  // (B,KVH,HD,S)
    unsigned short* __restrict__ Ob) {      // (token, NH*HD)
  __shared__ __align__(16) unsigned short Kt[64][128];   // [key][d-chunks, xor-swizzled]
  __shared__ __align__(16) unsigned short Vl[128][64];   // [d][key-chunks, xor-swizzled]
  __shared__ __align__(16) unsigned short Pl[4][16][72]; // per-wave [q][key], padded
  const int tid = threadIdx.x, wave = tid >> 6, lane = tid & 63;
  const int qb = blockIdx.x, h = blockIdx.y, b = blockIdx.z;
  const int kvh = h >> 2;  // N_REP = 4
  const int lql = lane & 15, lqh = lane >> 4;
  const int qrow = qb * 64 + wave * 16;

  const unsigned short* Qp = Qb + ((size_t)(b * NH + h) * S_LEN + qrow + lql) * HD + lqh * 8;
  bf16x8 qf[4];
#pragma unroll
  for (int kd = 0; kd < 4; kd++) qf[kd] = *(const bf16x8*)(Qp + kd * 32);

  const unsigned short* Kp = Kb + (size_t)(b * KVH + kvh) * S_LEN * HD;
  const unsigned short* Vp = Vt + (size_t)(b * KVH + kvh) * HD * S_LEN;
  // staging source offsets (per lane, constant across tiles)
  const int krow_in = lane >> 4;               // +0..3 within 4-row group
  const int kcol_sw = lane & 15;               // physical chunk
  const int vrow_in = lane >> 3;               // +0..7 within 8-row group
  const int vcol_off = ((lane & 7) ^ (lane >> 3)) * 8;

  float m_run[4], l_run[4];
  f32x4 Oacc[8] = {};
#pragma unroll
  for (int r = 0; r < 4; r++) { m_run[r] = -3.0e38f; l_run[r] = 0.0f; }

  for (int kt = 0; kt < S_LEN; kt += 64) {
    __syncthreads();
    // stage K tile (64 keys x 128 d), 4 async16 per wave
#pragma unroll
    for (int j = 0; j < 4; j++) {
      int rbase = wave * 16 + j * 4;
      int r = rbase + krow_in;
      async16(&Kt[rbase][0], Kp + (size_t)(kt + r) * HD + ((kcol_sw ^ (r & 7)) * 8));
    }
    // stage V^T tile (128 d x 64 keys), 4 async16 per wave
#pragma unroll
    for (int j = 0; j < 4; j++) {
      int dbase = wave * 32 + j * 8;
      int d = dbase + vrow_in;
      async16(&Vl[dbase][0], Vp + (size_t)d * S_LEN + kt + vcol_off);
    }
    __syncthreads();
    // S = Q K^T  (16 q x 64 keys per wave), log2 domain
    f32x4 sf[4] = {};
#pragma unroll
    for (int ni = 0; ni < 4; ni++) {
      const int ksw = lql & 7;
#pragma unroll
      for (int kd = 0; kd < 4; kd++) {
        bf16x8 kf = *(const bf16x8*)(&Kt[ni * 16 + lql][((kd * 4 + lqh) ^ ksw) * 8]);
        sf[ni] = __builtin_amdgcn_mfma_f32_16x16x32_bf16(qf[kd], kf, sf[ni], 0, 0, 0);
      }
    }
    // online softmax: row = lqh*4 + r, cols over the 16-lane group (masks 1/2/4/8)
    float mnew[4], alpha[4], psum[4];
#pragma unroll
    for (int r = 0; r < 4; r++) {
      float v = fmaxf(fmaxf(sf[0][r], sf[1][r]), fmaxf(sf[2][r], sf[3][r]));
      v = fmaxf(v, __shfl_xor(v, 1));
      v = fmaxf(v, __shfl_xor(v, 2));
      v = fmaxf(v, __shfl_xor(v, 4));
      v = fmaxf(v, __shfl_xor(v, 8));
      mnew[r] = fmaxf(m_run[r], v);
      alpha[r] = ex2(m_run[r] - mnew[r]);
      m_run[r] = mnew[r];
      psum[r] = 0.0f;
    }
#pragma unroll
    for (int ni = 0; ni < 4; ni++)
#pragma unroll
      for (int r = 0; r < 4; r++) {
        float p = ex2(sf[ni][r] - mnew[r]);
        psum[r] += p;
        union { float f; uint32_t u; } pv; pv.f = p;
        Pl[wave][lqh * 4 + r][ni * 16 + lql] = (unsigned short)(pv.u >> 16);
      }
#pragma unroll
    for (int r = 0; r < 4; r++) {
      float v = psum[r];
      v += __shfl_xor(v, 1);
      v += __shfl_xor(v, 2);
      v += __shfl_xor(v, 4);
      v += __shfl_xor(v, 8);
      l_run[r] = l_run[r] * alpha[r] + v;
    }
#pragma unroll
    for (int ni = 0; ni < 8; ni++)
#pragma unroll
      for (int r = 0; r < 4; r++) Oacc[ni][r] *= alpha[r];
    // O += P V  (P via per-wave LDS round-trip; same-wave DS ordering)
    bf16x8 pa[2];
#pragma unroll
    for (int ks = 0; ks < 2; ks++)
      pa[ks] = *(const bf16x8*)(&Pl[wave][lql][ks * 32 + lqh * 8]);
#pragma unroll
    for (int ni = 0; ni < 8; ni++) {
      const int ksw = lql & 7;
#pragma unroll
      for (int ks = 0; ks < 2; ks++) {
        bf16x8 vb = *(const bf16x8*)(&Vl[ni * 16 + lql][((ks * 4 + lqh) ^ ksw) * 8]);
        Oacc[ni] = __builtin_amdgcn_mfma_f32_16x16x32_bf16(pa[ks], vb, Oacc[ni], 0, 0, 0);
      }
    }
  }
#pragma unroll
  for (int r = 0; r < 4; r++) l_run[r] = 1.0f / l_run[r];
#pragma unroll
  for (int ni = 0; ni < 8; ni++)
#pragma unroll
    for (int r = 0; r < 4; r++) {
      int q = qrow + lqh * 4 + r;
      Ob[(size_t)(b * S_LEN + q) * DIM + h * HD + ni * 16 + lql] = f2bf(Oacc[ni][r] * l_run[r]);
    }
}

extern "C" void kernel_launch(void* const* d_in, const int* in_sizes, int n_in,
                              void* d_out, int out_size, void* d_ws, size_t ws_size,
                              hipStream_t stream) {
  (void)in_sizes; (void)n_in; (void)out_size; (void)ws_size;
  const float* x  = (const float*)d_in[0];
  const float* fc = (const float*)d_in[1];
  const float* fs = (const float*)d_in[2];
  const float* wq = (const float*)d_in[3];
  const float* wk = (const float*)d_in[4];
  const float* wv = (const float*)d_in[5];
  const float* wo = (const float*)d_in[6];
  float* out = (float*)d_out;
  char* ws = (char*)d_ws;

  const size_t MB = 1024 * 1024;
  unsigned short* xb    = (unsigned short*)(ws + 0);         // 32MB; dead after gemm1
  unsigned short* attnb = (unsigned short*)(ws + 0);         // reuses xb slot
  unsigned short* wqkvt = (unsigned short*)(ws + 32 * MB);   // 48MB; dead after gemm1
  unsigned short* Qb    = (unsigned short*)(ws + 32 * MB);   // 32MB, reuses wqkvt
  unsigned short* Kb    = (unsigned short*)(ws + 64 * MB);   // 8MB
  unsigned short* Vt    = (unsigned short*)(ws + 72 * MB);   // 8MB
  unsigned short* wot   = (unsigned short*)(ws + 80 * MB);   // 32MB
  unsigned short* qkv   = (unsigned short*)(ws + 112 * MB);  // 48MB

  cvt_x_kernel<<<16384, 256, 0, stream>>>(x, xb);
  wtrans_kernel<<<dim3(64, 64), 256, 0, stream>>>(wq, wqkvt, 4096);
  wtrans_kernel<<<dim3(16, 64), 256, 0, stream>>>(wk, wqkvt + (size_t)4096 * 4096, 1024);
  wtrans_kernel<<<dim3(16, 64), 256, 0, stream>>>(wv, wqkvt + (size_t)5120 * 4096, 1024);
  wtrans_kernel<<<dim3(64, 64), 256, 0, stream>>>(wo, wot, 4096);
  // QKV projection: (4096 x 4096) @ (4096 x 6144) -> bf16
  gemm_bt_kernel<true><<<dim3(DQKV / 128, 32), 256, 0, stream>>>(xb, wqkvt, qkv, DIM, DQKV);
  // RoPE + relayout; Q scale = (1/sqrt(128)) * log2(e) for log2-domain softmax
  rope_kernel<<<8192, 256, 0, stream>>>(qkv, fc, fs, Qb, NH, 5, 0.12751879505099168f);
  rope_kernel<<<2048, 256, 0, stream>>>(qkv + 4096, fc, fs, Kb, KVH, 3, 1.0f);
  vtrans_kernel<<<dim3(32, 4, 32), 256, 0, stream>>>(qkv + 5120, Vt);
  // attention
  attn_kernel<<<dim3(16, NH, B_SZ), 256, 0, stream>>>(Qb, Kb, Vt, attnb);
  // out projection: fp32 out
  gemm_bt_kernel<false><<<dim3(32, 32), 256, 0, stream>>>(attnb, wot, out, DIM, DIM);
}

// Round 4
// 779.850 us; speedup vs baseline: 1.1373x; 1.0313x over previous
//
#include <hip/hip_runtime.h>
#include <cstdint>

#define B_SZ 4
#define S_LEN 1024
#define DIM 4096
#define NH 32
#define KVH 8
#define HD 128
#define DQKV 6144  // 4096 Q + 1024 K + 1024 V

typedef __bf16 bf16x8 __attribute__((ext_vector_type(8)));
typedef float f32x4 __attribute__((ext_vector_type(4)));
typedef float f32x16 __attribute__((ext_vector_type(16)));

__device__ __forceinline__ unsigned short f2bf(float f) {
  union { float f; uint32_t u; } v; v.f = f;
  uint32_t u = v.u;
  return (unsigned short)((u + 0x7fffu + ((u >> 16) & 1u)) >> 16);
}
__device__ __forceinline__ float bf2f(unsigned short h) {
  union { uint32_t u; float f; } v; v.u = ((uint32_t)h) << 16;
  return v.f;
}
__device__ __forceinline__ float ex2(float x) {
#if __has_builtin(__builtin_amdgcn_exp2f)
  return __builtin_amdgcn_exp2f(x);
#else
  return exp2f(x);
#endif
}

// async global->LDS, 16B per lane; LDS dest = wave-uniform base + lane*16
__device__ __forceinline__ void async16(void* lds, const void* g) {
  __builtin_amdgcn_global_load_lds(
      (const __attribute__((address_space(1))) void*)g,
      (__attribute__((address_space(3))) void*)lds, 16, 0, 0);
}

// ---------------- elementwise f32 -> bf16 ----------------
__global__ void cvt_x_kernel(const float* __restrict__ x, unsigned short* __restrict__ xb) {
  size_t i = ((size_t)blockIdx.x * 256 + threadIdx.x) * 4;
  float4 v = *(const float4*)(x + i);
  ushort4 o;
  o.x = f2bf(v.x); o.y = f2bf(v.y); o.z = f2bf(v.z); o.w = f2bf(v.w);
  *(ushort4*)(xb + i) = o;
}

// ---------------- weight transpose+convert: w (K x N f32) -> wt (N x K bf16, ld=4096) ----
__global__ void wtrans_kernel(const float* __restrict__ w, unsigned short* __restrict__ wt, int N) {
  __shared__ float tile[64][65];
  int n0 = blockIdx.x * 64, k0 = blockIdx.y * 64;
  int tx = threadIdx.x & 63, ty = threadIdx.x >> 6;
#pragma unroll
  for (int i = 0; i < 16; i++) {
    int k = ty + i * 4;
    tile[k][tx] = w[(size_t)(k0 + k) * N + n0 + tx];
  }
  __syncthreads();
  int c = threadIdx.x & 31, ny = threadIdx.x >> 5;
#pragma unroll
  for (int i = 0; i < 8; i++) {
    int n = ny + i * 8;
    ushort2 o;
    o.x = f2bf(tile[2 * c][n]);
    o.y = f2bf(tile[2 * c + 1][n]);
    *(ushort2*)(wt + (size_t)(n0 + n) * DIM + k0 + 2 * c) = o;
  }
}

// ---------------- GEMM: C(MxN) = A(MxK bf16) * Bt(NxK bf16)^T ----------------
// 128x128 tile, BK=64, 4 waves (2x2 of 64x64), 2x2 of 32x32x16 MFMA per wave.
// XOR swizzle: row r's logical 16B-chunk c stored at physical c ^ (r&7).
// Staging: 8 async16/wave (each 8 rows x 8 chunks, lane = r_in*8 + p).
template <bool OUT_BF16>
__global__ __launch_bounds__(256, 3) void gemm_bt_kernel(
    const unsigned short* __restrict__ A, const unsigned short* __restrict__ Bt,
    void* __restrict__ Cout, int Kdim, int ldc) {
  __shared__ __align__(16) unsigned short lA[128 * 64];
  __shared__ __align__(16) unsigned short lB[128 * 64];
  const int tid = threadIdx.x;
  const int wave = tid >> 6, lane = tid & 63;
  const int m0 = blockIdx.y * 128, n0 = blockIdx.x * 128;
  const int r_in = lane >> 3;                 // 0..7 within 8-row group
  const int csw = ((lane & 7) ^ r_in) * 8;    // swizzled source col (elems)
  const int rA = wave * 32;                   // wave's staging window
  const unsigned short* gA = A + (size_t)(m0 + rA + r_in) * Kdim + csw;
  const unsigned short* gB = Bt + (size_t)(n0 + rA + r_in) * Kdim + csw;
  unsigned short* lAw = lA + rA * 64;
  unsigned short* lBw = lB + rA * 64;
  const int wm = (wave & 1) * 64, wn = (wave >> 1) * 64;
  const int l31 = lane & 31, lh = lane >> 5, l7 = lane & 7;
  f32x16 acc[2][2] = {};
  for (int kk = 0; kk < Kdim; kk += 64) {
    __syncthreads();
#pragma unroll
    for (int j = 0; j < 4; j++)
      async16(lAw + j * 512, gA + (size_t)(j * 8) * Kdim + kk);
#pragma unroll
    for (int j = 0; j < 4; j++)
      async16(lBw + j * 512, gB + (size_t)(j * 8) * Kdim + kk);
    __syncthreads();
#pragma unroll
    for (int s = 0; s < 4; s++) {
      const int pc = ((s * 2 + lh) ^ l7) * 8;  // physical chunk for k-window s
      bf16x8 a0 = *(const bf16x8*)(lA + (wm + l31) * 64 + pc);
      bf16x8 a1 = *(const bf16x8*)(lA + (wm + 32 + l31) * 64 + pc);
      bf16x8 b0 = *(const bf16x8*)(lB + (wn + l31) * 64 + pc);
      bf16x8 b1 = *(const bf16x8*)(lB + (wn + 32 + l31) * 64 + pc);
      acc[0][0] = __builtin_amdgcn_mfma_f32_32x32x16_bf16(a0, b0, acc[0][0], 0, 0, 0);
      acc[0][1] = __builtin_amdgcn_mfma_f32_32x32x16_bf16(a0, b1, acc[0][1], 0, 0, 0);
      acc[1][0] = __builtin_amdgcn_mfma_f32_32x32x16_bf16(a1, b0, acc[1][0], 0, 0, 0);
      acc[1][1] = __builtin_amdgcn_mfma_f32_32x32x16_bf16(a1, b1, acc[1][1], 0, 0, 0);
    }
  }
  // 32x32 C/D layout: col = lane&31, row = (reg&3) + 8*(reg>>2) + 4*(lane>>5)  [m74/m101]
#pragma unroll
  for (int mt = 0; mt < 2; mt++)
#pragma unroll
    for (int nt = 0; nt < 2; nt++)
#pragma unroll
      for (int reg = 0; reg < 16; reg++) {
        int row = m0 + wm + mt * 32 + (reg & 3) + 8 * (reg >> 2) + 4 * lh;
        int col = n0 + wn + nt * 32 + l31;
        float v = acc[mt][nt][reg];
        if (OUT_BF16)
          ((unsigned short*)Cout)[(size_t)row * ldc + col] = f2bf(v);
        else
          ((float*)Cout)[(size_t)row * ldc + col] = v;
      }
}

// ---------------- RoPE + relayout: qkv rows (token, DQKV) -> (B, H, S, HD) -------------
__global__ void rope_kernel(const unsigned short* __restrict__ src, const float* __restrict__ fc,
                            const float* __restrict__ fs, unsigned short* __restrict__ dst,
                            int nheads, int hshift, float scale) {
  int idx = blockIdx.x * 256 + threadIdx.x;
  int f4 = idx & 15;
  int rest = idx >> 4;
  int hh = rest & (nheads - 1);
  int t = rest >> hshift;
  int s = t & (S_LEN - 1);
  int b = t >> 10;
  union { uint4 v; unsigned short u[8]; } in, out;
  in.v = *(const uint4*)(src + (size_t)t * DQKV + hh * HD + f4 * 8);
  union { float4 v; float f[4]; } c4, s4;
  c4.v = *(const float4*)(fc + s * 64 + f4 * 4);
  s4.v = *(const float4*)(fs + s * 64 + f4 * 4);
#pragma unroll
  for (int j = 0; j < 4; j++) {
    float xr = bf2f(in.u[2 * j]), xi = bf2f(in.u[2 * j + 1]);
    float cc = c4.f[j], ss = s4.f[j];
    out.u[2 * j] = f2bf((xr * cc - xi * ss) * scale);
    out.u[2 * j + 1] = f2bf((xr * ss + xi * cc) * scale);
  }
  *(uint4*)(dst + ((size_t)(b * nheads + hh) * S_LEN + s) * HD + f4 * 8) = out.v;
}

// ---------------- V transpose: qkv V cols (token, kvh*HD+d) -> Vt (B,KVH,HD,S) ----------
__global__ void vtrans_kernel(const unsigned short* __restrict__ src, unsigned short* __restrict__ Vt) {
  __shared__ __align__(16) unsigned short tile[32][33];
  int s0 = blockIdx.x * 32, d0 = blockIdx.y * 32, bk = blockIdx.z;
  int tx = threadIdx.x & 31, ty = threadIdx.x >> 5;
#pragma unroll
  for (int i = 0; i < 4; i++) {
    int s = ty + i * 8;
    tile[s][tx] = src[(size_t)((bk >> 3) * S_LEN + s0 + s) * DQKV + (bk & 7) * HD + d0 + tx];
  }
  __syncthreads();
#pragma unroll
  for (int i = 0; i < 4; i++) {
    int d = ty + i * 8;
    Vt[((size_t)bk * HD + d0 + d) * S_LEN + s0 + tx] = tile[tx][d];
  }
}

// ---------------- flash attention (non-causal, full 1024 keys) ----------------
__global__ __launch_bounds__(256, 3) void attn_kernel(
    const unsigned short* __restrict__ Qb,  // (B,NH,S,HD)
    const unsigned short* __restrict__ Kb,  // (B,KVH,S,HD)
    const unsigned short* __restrict__ Vt,  // (B,KVH,HD,S)
    unsigned short* __restrict__ Ob) {      // (token, NH*HD)
  __shared__ __align__(16) unsigned short Kt[64][128];   // [key][d-chunks, xor-swizzled]
  __shared__ __align__(16) unsigned short Vl[128][64];   // [d][key-chunks, xor-swizzled]
  __shared__ __align__(16) unsigned short Pl[4][16][72]; // per-wave [q][key], padded
  const int tid = threadIdx.x, wave = tid >> 6, lane = tid & 63;
  const int qb = blockIdx.x, h = blockIdx.y, b = blockIdx.z;
  const int kvh = h >> 2;  // N_REP = 4
  const int lql = lane & 15, lqh = lane >> 4;
  const int qrow = qb * 64 + wave * 16;

  const unsigned short* Qp = Qb + ((size_t)(b * NH + h) * S_LEN + qrow + lql) * HD + lqh * 8;
  bf16x8 qf[4];
#pragma unroll
  for (int kd = 0; kd < 4; kd++) qf[kd] = *(const bf16x8*)(Qp + kd * 32);

  const unsigned short* Kp = Kb + (size_t)(b * KVH + kvh) * S_LEN * HD;
  const unsigned short* Vp = Vt + (size_t)(b * KVH + kvh) * HD * S_LEN;
  const int krow_in = lane >> 4;               // +0..3 within 4-row group
  const int kcol_sw = lane & 15;               // physical chunk
  const int vrow_in = lane >> 3;               // +0..7 within 8-row group
  const int vcol_off = ((lane & 7) ^ (lane >> 3)) * 8;

  float m_run[4], l_run[4];
  f32x4 Oacc[8] = {};
#pragma unroll
  for (int r = 0; r < 4; r++) { m_run[r] = -3.0e38f; l_run[r] = 0.0f; }

  for (int kt = 0; kt < S_LEN; kt += 64) {
    __syncthreads();
#pragma unroll
    for (int j = 0; j < 4; j++) {
      int rbase = wave * 16 + j * 4;
      int r = rbase + krow_in;
      async16(&Kt[rbase][0], Kp + (size_t)(kt + r) * HD + ((kcol_sw ^ (r & 7)) * 8));
    }
#pragma unroll
    for (int j = 0; j < 4; j++) {
      int dbase = wave * 32 + j * 8;
      int d = dbase + vrow_in;
      async16(&Vl[dbase][0], Vp + (size_t)d * S_LEN + kt + vcol_off);
    }
    __syncthreads();
    f32x4 sf[4] = {};
#pragma unroll
    for (int ni = 0; ni < 4; ni++) {
      const int ksw = lql & 7;
#pragma unroll
      for (int kd = 0; kd < 4; kd++) {
        bf16x8 kf = *(const bf16x8*)(&Kt[ni * 16 + lql][((kd * 4 + lqh) ^ ksw) * 8]);
        sf[ni] = __builtin_amdgcn_mfma_f32_16x16x32_bf16(qf[kd], kf, sf[ni], 0, 0, 0);
      }
    }
    float mnew[4], alpha[4], psum[4];
#pragma unroll
    for (int r = 0; r < 4; r++) {
      float v = fmaxf(fmaxf(sf[0][r], sf[1][r]), fmaxf(sf[2][r], sf[3][r]));
      v = fmaxf(v, __shfl_xor(v, 1));
      v = fmaxf(v, __shfl_xor(v, 2));
      v = fmaxf(v, __shfl_xor(v, 4));
      v = fmaxf(v, __shfl_xor(v, 8));
      mnew[r] = fmaxf(m_run[r], v);
      alpha[r] = ex2(m_run[r] - mnew[r]);
      m_run[r] = mnew[r];
      psum[r] = 0.0f;
    }
#pragma unroll
    for (int ni = 0; ni < 4; ni++)
#pragma unroll
      for (int r = 0; r < 4; r++) {
        float p = ex2(sf[ni][r] - mnew[r]);
        psum[r] += p;
        union { float f; uint32_t u; } pv; pv.f = p;
        Pl[wave][lqh * 4 + r][ni * 16 + lql] = (unsigned short)(pv.u >> 16);
      }
#pragma unroll
    for (int r = 0; r < 4; r++) {
      float v = psum[r];
      v += __shfl_xor(v, 1);
      v += __shfl_xor(v, 2);
      v += __shfl_xor(v, 4);
      v += __shfl_xor(v, 8);
      l_run[r] = l_run[r] * alpha[r] + v;
    }
#pragma unroll
    for (int ni = 0; ni < 8; ni++)
#pragma unroll
      for (int r = 0; r < 4; r++) Oacc[ni][r] *= alpha[r];
    bf16x8 pa[2];
#pragma unroll
    for (int ks = 0; ks < 2; ks++)
      pa[ks] = *(const bf16x8*)(&Pl[wave][lql][ks * 32 + lqh * 8]);
#pragma unroll
    for (int ni = 0; ni < 8; ni++) {
      const int ksw = lql & 7;
#pragma unroll
      for (int ks = 0; ks < 2; ks++) {
        bf16x8 vb = *(const bf16x8*)(&Vl[ni * 16 + lql][((ks * 4 + lqh) ^ ksw) * 8]);
        Oacc[ni] = __builtin_amdgcn_mfma_f32_16x16x32_bf16(pa[ks], vb, Oacc[ni], 0, 0, 0);
      }
    }
  }
#pragma unroll
  for (int r = 0; r < 4; r++) l_run[r] = 1.0f / l_run[r];
#pragma unroll
  for (int ni = 0; ni < 8; ni++)
#pragma unroll
    for (int r = 0; r < 4; r++) {
      int q = qrow + lqh * 4 + r;
      Ob[(size_t)(b * S_LEN + q) * DIM + h * HD + ni * 16 + lql] = f2bf(Oacc[ni][r] * l_run[r]);
    }
}

extern "C" void kernel_launch(void* const* d_in, const int* in_sizes, int n_in,
                              void* d_out, int out_size, void* d_ws, size_t ws_size,
                              hipStream_t stream) {
  (void)in_sizes; (void)n_in; (void)out_size; (void)ws_size;
  const float* x  = (const float*)d_in[0];
  const float* fc = (const float*)d_in[1];
  const float* fs = (const float*)d_in[2];
  const float* wq = (const float*)d_in[3];
  const float* wk = (const float*)d_in[4];
  const float* wv = (const float*)d_in[5];
  const float* wo = (const float*)d_in[6];
  float* out = (float*)d_out;
  char* ws = (char*)d_ws;

  const size_t MB = 1024 * 1024;
  unsigned short* xb    = (unsigned short*)(ws + 0);         // 32MB; dead after gemm1
  unsigned short* attnb = (unsigned short*)(ws + 0);         // reuses xb slot
  unsigned short* wqkvt = (unsigned short*)(ws + 32 * MB);   // 48MB; dead after gemm1
  unsigned short* Qb    = (unsigned short*)(ws + 32 * MB);   // 32MB, reuses wqkvt
  unsigned short* Kb    = (unsigned short*)(ws + 64 * MB);   // 8MB
  unsigned short* Vt    = (unsigned short*)(ws + 72 * MB);   // 8MB
  unsigned short* wot   = (unsigned short*)(ws + 80 * MB);   // 32MB
  unsigned short* qkv   = (unsigned short*)(ws + 112 * MB);  // 48MB

  cvt_x_kernel<<<16384, 256, 0, stream>>>(x, xb);
  wtrans_kernel<<<dim3(64, 64), 256, 0, stream>>>(wq, wqkvt, 4096);
  wtrans_kernel<<<dim3(16, 64), 256, 0, stream>>>(wk, wqkvt + (size_t)4096 * 4096, 1024);
  wtrans_kernel<<<dim3(16, 64), 256, 0, stream>>>(wv, wqkvt + (size_t)5120 * 4096, 1024);
  wtrans_kernel<<<dim3(64, 64), 256, 0, stream>>>(wo, wot, 4096);
  // QKV projection: (4096 x 4096) @ (4096 x 6144) -> bf16
  gemm_bt_kernel<true><<<dim3(DQKV / 128, 32), 256, 0, stream>>>(xb, wqkvt, qkv, DIM, DQKV);
  // RoPE + relayout; Q scale = (1/sqrt(128)) * log2(e) for log2-domain softmax
  rope_kernel<<<8192, 256, 0, stream>>>(qkv, fc, fs, Qb, NH, 5, 0.12751879505099168f);
  rope_kernel<<<2048, 256, 0, stream>>>(qkv + 4096, fc, fs, Kb, KVH, 3, 1.0f);
  vtrans_kernel<<<dim3(32, 4, 32), 256, 0, stream>>>(qkv + 5120, Vt);
  // attention
  attn_kernel<<<dim3(16, NH, B_SZ), 256, 0, stream>>>(Qb, Kb, Vt, attnb);
  // out projection: fp32 out
  gemm_bt_kernel<false><<<dim3(32, 32), 256, 0, stream>>>(attnb, wot, out, DIM, DIM);
}